// Round 4
// baseline (115.538 us; speedup 1.0000x reference)
//
#include <hip/hip_runtime.h>
#include <hip/hip_bf16.h>
#include <stdint.h>

#define NB 8192
#define DK 256
#define GAMMA 10.0f

typedef short short8 __attribute__((ext_vector_type(8)));
typedef float f32x4 __attribute__((ext_vector_type(4)));

__device__ __forceinline__ unsigned short f32_to_bf16(float f) {
  uint32_t u = __builtin_bit_cast(uint32_t, f);
  u += 0x7FFFu + ((u >> 16) & 1u);   // RNE
  return (unsigned short)(u >> 16);
}

// One wave per row: 1/max(||row||,eps); gamma folded into e side; store bf16.
__global__ __launch_bounds__(256) void norm_kernel(const float* __restrict__ e,
                                                   const float* __restrict__ v,
                                                   unsigned short* __restrict__ ebf,
                                                   unsigned short* __restrict__ vbf) {
  int wave = threadIdx.x >> 6;
  int lane = threadIdx.x & 63;
  int row = blockIdx.x * 4 + wave;
  const float* src;
  unsigned short* dst;
  float mul;
  if (row < NB) {
    src = e + (size_t)row * DK; dst = ebf + (size_t)row * DK; mul = GAMMA;
  } else {
    src = v + (size_t)(row - NB) * DK; dst = vbf + (size_t)(row - NB) * DK; mul = 1.0f;
  }
  float4 x = reinterpret_cast<const float4*>(src)[lane];
  float ss = x.x * x.x + x.y * x.y + x.z * x.z + x.w * x.w;
  #pragma unroll
  for (int off = 32; off >= 1; off >>= 1) ss += __shfl_xor(ss, off);
  float s = mul / fmaxf(sqrtf(ss), 1e-8f);
  ushort4 o;
  o.x = f32_to_bf16(x.x * s);
  o.y = f32_to_bf16(x.y * s);
  o.z = f32_to_bf16(x.z * s);
  o.w = f32_to_bf16(x.w * s);
  reinterpret_cast<ushort4*>(dst)[lane] = o;
}

// Barrier-free, LDS-free: A-panel (wave's 64 e-rows x 256 k) lives in regs
// A[4][8]; B fragments gathered straight from L2-resident vbf with a
// ping-pong register pair (Fa/Fb). No __syncthreads anywhere -> no vmcnt(0)
// lockstep drains; waves self-pipeline and epilogue VALU overlaps other
// waves' MFMA (m114).
__global__ __launch_bounds__(512, 2) void score_kernel(const unsigned short* __restrict__ ebf,
                                                       const unsigned short* __restrict__ vbf,
                                                       float* __restrict__ out) {
  const int tid = threadIdx.x;
  const int w = tid >> 6;          // 0..7
  const int lane = tid & 63;
  const int lo16 = lane & 15;
  const int q4 = lane >> 4;        // 0..3
  const int wr = w >> 2;           // 0..1 (M half, 64 rows)
  const int wc = w & 3;            // 0..3 (N quarter, 64 cols)

  // 256 blocks = 64 bi x 4 jc; XCD pair shares one jc chunk (L2 locality).
  int id = blockIdx.x;
  int xcd = id & 7;
  int s5 = id >> 3;                 // 0..31
  int jc = xcd >> 1;                // 0..3
  int bi = s5 | ((xcd & 1) << 5);   // 0..63

  // ---- A panel direct to registers: row = bi*128 + wr*64 + m*16 + lo16,
  //      k chunk s: bytes s*64 + q4*16 (lane holds k = s*32 + q4*8 .. +8) ----
  const char* eBase = (const char*)ebf;
  short8 A[4][8];
  #pragma unroll
  for (int m = 0; m < 4; ++m) {
    const char* rp = eBase + (size_t)(bi * 128 + wr * 64 + m * 16 + lo16) * 512 + q4 * 16;
    #pragma unroll
    for (int s = 0; s < 8; ++s)
      A[m][s] = *(const short8*)(rp + s * 64);
  }

  // ---- B fragment base pointers (per n), advanced by 256 rows per j ----
  const char* vBase = (const char*)vbf + (size_t)(jc * 2048) * 512;
  const char* p0 = vBase + (size_t)(wc * 64 + 0 * 16 + lo16) * 512 + q4 * 16;
  const char* p1 = vBase + (size_t)(wc * 64 + 1 * 16 + lo16) * 512 + q4 * 16;
  const char* p2 = vBase + (size_t)(wc * 64 + 2 * 16 + lo16) * 512 + q4 * 16;
  const char* p3 = vBase + (size_t)(wc * 64 + 3 * 16 + lo16) * 512 + q4 * 16;

  f32x4 acc[4][4];
  #pragma unroll
  for (int m = 0; m < 4; ++m)
    #pragma unroll
    for (int n = 0; n < 4; ++n)
      #pragma unroll
      for (int q = 0; q < 4; ++q)
        acc[m][n][q] = 0.0f;

#define LOADF(F, OFF)                                  \
  do {                                                 \
    F[0] = *(const short8*)(p0 + (OFF));               \
    F[1] = *(const short8*)(p1 + (OFF));               \
    F[2] = *(const short8*)(p2 + (OFF));               \
    F[3] = *(const short8*)(p3 + (OFF));               \
  } while (0)

#define MM(F, S)                                                                      \
  do {                                                                               \
    _Pragma("unroll")                                                                \
    for (int m = 0; m < 4; ++m) {                                                    \
      acc[m][0] = __builtin_amdgcn_mfma_f32_16x16x32_bf16(A[m][S], F[0], acc[m][0], 0, 0, 0); \
      acc[m][1] = __builtin_amdgcn_mfma_f32_16x16x32_bf16(A[m][S], F[1], acc[m][1], 0, 0, 0); \
      acc[m][2] = __builtin_amdgcn_mfma_f32_16x16x32_bf16(A[m][S], F[2], acc[m][2], 0, 0, 0); \
      acc[m][3] = __builtin_amdgcn_mfma_f32_16x16x32_bf16(A[m][S], F[3], acc[m][3], 0, 0, 0); \
    }                                                                                \
  } while (0)

  short8 Fa[4], Fb[4];
  LOADF(Fa, 0);

  for (int j = 0; j < 8; ++j) {
    LOADF(Fb, 1 * 64);  MM(Fa, 0);
    LOADF(Fa, 2 * 64);  MM(Fb, 1);
    LOADF(Fb, 3 * 64);  MM(Fa, 2);
    LOADF(Fa, 4 * 64);  MM(Fb, 3);
    LOADF(Fb, 5 * 64);  MM(Fa, 4);
    LOADF(Fa, 6 * 64);  MM(Fb, 5);
    LOADF(Fb, 7 * 64);  MM(Fa, 6);
    p0 += 131072; p1 += 131072; p2 += 131072; p3 += 131072;   // next 256 v-rows
    if (j < 7) LOADF(Fa, 0);     // prefetch next j-tile under the epilogue
    MM(Fb, 7);

    // ---- per-j-tile epilogue: E = exp(acc); row/col sums; reset acc ----
    // C/D layout: col(lane&15) = B/N side, row((lane>>4)*4+reg) = A/M side.
    int colbase = (jc * 8 + j) * 256 + wc * 64;
    float colpart[4] = {0.f, 0.f, 0.f, 0.f};
    #pragma unroll
    for (int m = 0; m < 4; ++m) {
      float rowpart[4] = {0.f, 0.f, 0.f, 0.f};
      #pragma unroll
      for (int n = 0; n < 4; ++n) {
        #pragma unroll
        for (int g = 0; g < 4; ++g) {
          float ev = __expf(acc[m][n][g]);
          rowpart[g] += ev;
          colpart[n] += ev;
          acc[m][n][g] = 0.0f;
        }
      }
      #pragma unroll
      for (int g = 0; g < 4; ++g) {
        float rs = rowpart[g];
        rs += __shfl_xor(rs, 1);
        rs += __shfl_xor(rs, 2);
        rs += __shfl_xor(rs, 4);
        rs += __shfl_xor(rs, 8);
        if (lo16 == m * 4 + g) {
          int row = bi * 128 + wr * 64 + m * 16 + q4 * 4 + g;
          atomicAdd(&out[row], rs);
        }
      }
    }
    #pragma unroll
    for (int n = 0; n < 4; ++n) {
      float cs = colpart[n];
      cs += __shfl_xor(cs, 16);
      cs += __shfl_xor(cs, 32);
      if (q4 == n) {
        atomicAdd(&out[NB + colbase + n * 16 + lo16], cs);
      }
    }
  }
#undef LOADF
#undef MM
}

extern "C" void kernel_launch(void* const* d_in, const int* in_sizes, int n_in,
                              void* d_out, int out_size, void* d_ws, size_t ws_size,
                              hipStream_t stream) {
  const float* e = (const float*)d_in[0];
  const float* v = (const float*)d_in[1];
  float* out = (float*)d_out;
  unsigned short* ebf = (unsigned short*)d_ws;
  unsigned short* vbf = ebf + (size_t)NB * DK;
  hipMemsetAsync(d_out, 0, (size_t)2 * NB * sizeof(float), stream);
  hipLaunchKernelGGL(norm_kernel, dim3((2 * NB) / 4), dim3(256), 0, stream, e, v, ebf, vbf);
  hipLaunchKernelGGL(score_kernel, dim3(256), dim3(512), 0, stream, ebf, vbf, out);
}

// Round 5
// 90.872 us; speedup vs baseline: 1.2714x; 1.2714x over previous
//
#include <hip/hip_runtime.h>
#include <hip/hip_bf16.h>
#include <stdint.h>

#define NB 8192
#define DK 256
// gamma * log2(e): epilogue uses native exp2
#define GSCALE 14.426950408889634f

typedef short short8 __attribute__((ext_vector_type(8)));
typedef float f32x4 __attribute__((ext_vector_type(4)));

__device__ __forceinline__ unsigned short f32_to_bf16(float f) {
  uint32_t u = __builtin_bit_cast(uint32_t, f);
  u += 0x7FFFu + ((u >> 16) & 1u);   // RNE
  return (unsigned short)(u >> 16);
}

// One wave per row: 1/max(||row||,eps); gamma*log2e folded into e side; store bf16.
__global__ __launch_bounds__(256) void norm_kernel(const float* __restrict__ e,
                                                   const float* __restrict__ v,
                                                   unsigned short* __restrict__ ebf,
                                                   unsigned short* __restrict__ vbf) {
  int wave = threadIdx.x >> 6;
  int lane = threadIdx.x & 63;
  int row = blockIdx.x * 4 + wave;
  const float* src;
  unsigned short* dst;
  float mul;
  if (row < NB) {
    src = e + (size_t)row * DK; dst = ebf + (size_t)row * DK; mul = GSCALE;
  } else {
    src = v + (size_t)(row - NB) * DK; dst = vbf + (size_t)(row - NB) * DK; mul = 1.0f;
  }
  float4 x = reinterpret_cast<const float4*>(src)[lane];
  float ss = x.x * x.x + x.y * x.y + x.z * x.z + x.w * x.w;
  #pragma unroll
  for (int off = 32; off >= 1; off >>= 1) ss += __shfl_xor(ss, off);
  float s = mul / fmaxf(sqrtf(ss), 1e-8f);
  ushort4 o;
  o.x = f32_to_bf16(x.x * s);
  o.y = f32_to_bf16(x.y * s);
  o.z = f32_to_bf16(x.z * s);
  o.w = f32_to_bf16(x.w * s);
  reinterpret_cast<ushort4*>(dst)[lane] = o;
}

// A-in-registers + LDS-broadcast B with counted-vmcnt pipeline (T3/T4):
// 256 blocks (1/CU), 8 waves (2x4). Block: 128 e-rows x 2048 v-cols.
// 32 chunks of B ([256 v-rows][64 k] = 32 KiB), double-buffered; stage(c+1)
// issued each phase, s_waitcnt vmcnt(4) waits ONLY chunk c (never drains the
// in-flight prefetch), raw s_barrier (no compiler vmcnt(0)).
__global__ __launch_bounds__(512, 2) void score_kernel(const unsigned short* __restrict__ ebf,
                                                       const unsigned short* __restrict__ vbf,
                                                       float* __restrict__ out) {
  __shared__ unsigned short smem[2][16384];   // 2 x 32 KiB

  const int tid = threadIdx.x;
  const int w = tid >> 6;          // 0..7
  const int lane = tid & 63;
  const int lo16 = lane & 15;
  const int q4 = lane >> 4;        // 0..3
  const int wr = w >> 2;           // 0..1 (M half, 64 rows)
  const int wc = w & 3;            // 0..3 (N quarter, 64 cols)

  // 256 blocks = 64 bi x 4 jc; XCD pair shares one jc chunk (L2 locality).
  int id = blockIdx.x;
  int xcd = id & 7;
  int s5 = id >> 3;
  int jc = xcd >> 1;                // 0..3
  int bi = s5 | ((xcd & 1) << 5);   // 0..63

  // ---- A panel direct to registers (one-time): row = bi*128+wr*64+m*16+lo16,
  //      A[m][s] holds k = s*32 + q4*8 .. +8 ----
  const char* eBase = (const char*)ebf;
  short8 A[4][8];
  #pragma unroll
  for (int m = 0; m < 4; ++m) {
    const char* rp = eBase + (size_t)(bi * 128 + wr * 64 + m * 16 + lo16) * 512 + q4 * 16;
    #pragma unroll
    for (int s = 0; s < 8; ++s)
      A[m][s] = *(const short8*)(rp + s * 64);
  }

  const char* vC = (const char*)vbf + (size_t)(jc * 2048) * 512;

  // Stage chunk c (j = c>>2 of 8, kt = c&3 of 4) into smem[c&1], swizzled.
  auto stageB = [&](int c) {
    int buf = c & 1;
    const char* vP = vC + (size_t)(c >> 2) * 256 * 512;
    int ktoff = (c & 3) * 128;
    #pragma unroll
    for (int u = 0; u < 4; ++u) {
      int p = ((w * 4 + u) * 64 + lane) * 16;       // linear byte in 32 KiB chunk
      int r = p >> 7;                                // v-row (128 B rows)
      int lc = (p & 127) ^ ((r & 7) << 4);           // inverse-swizzled col
      size_t goff = (size_t)r * 512 + ktoff + lc;
      unsigned short* dst = &smem[buf][(w * 4 + u) * 512];
      __builtin_amdgcn_global_load_lds((const __attribute__((address_space(1))) uint32_t*)(vP + goff),
                                       (__attribute__((address_space(3))) uint32_t*)dst, 16, 0, 0);
    }
  };

  f32x4 acc[4][4];
  #pragma unroll
  for (int m = 0; m < 4; ++m)
    #pragma unroll
    for (int n = 0; n < 4; ++n)
      #pragma unroll
      for (int q = 0; q < 4; ++q)
        acc[m][n][q] = 0.0f;

  float rowAcc[4][4];
  #pragma unroll
  for (int m = 0; m < 4; ++m)
    #pragma unroll
    for (int g = 0; g < 4; ++g)
      rowAcc[m][g] = 0.0f;

  stageB(0);

  for (int j8 = 0; j8 < 8; ++j8) {
    #pragma unroll
    for (int kt = 0; kt < 4; ++kt) {
      const int c = j8 * 4 + kt;
      stageB((c + 1) & 31);                          // prefetch stays in flight
      asm volatile("s_waitcnt vmcnt(4)" ::: "memory");   // chunk c done, c+1 pending
      __builtin_amdgcn_s_barrier();                  // all waves' chunk-c writes visible
      asm volatile("" ::: "memory");
      const char* LB = (const char*)&smem[kt & 1][0];
      short8 bfr[2][4];
      #pragma unroll
      for (int ks = 0; ks < 2; ++ks)
        #pragma unroll
        for (int n = 0; n < 4; ++n) {
          int row = wc * 64 + n * 16 + lo16;
          int byte = row * 128 + ((ks * 64 + q4 * 16) ^ ((row & 7) << 4));
          bfr[ks][n] = *(const short8*)(LB + byte);
        }
      asm volatile("s_waitcnt lgkmcnt(0)" ::: "memory");
      __builtin_amdgcn_sched_barrier(0);             // rule #18: pin MFMA after wait
      __builtin_amdgcn_s_setprio(1);
      #pragma unroll
      for (int ks = 0; ks < 2; ++ks)
        #pragma unroll
        for (int m = 0; m < 4; ++m)
          #pragma unroll
          for (int n = 0; n < 4; ++n)
            acc[m][n] = __builtin_amdgcn_mfma_f32_16x16x32_bf16(A[m][kt * 2 + ks], bfr[ks][n], acc[m][n], 0, 0, 0);
      __builtin_amdgcn_s_setprio(0);

      if (kt == 3) {
        // ---- per-j epilogue: E = exp2(acc); rows -> regs, cols -> atomics ----
        // C/D layout: col = lane&15 (B side), row = (lane>>4)*4 + reg (A side).
        int colbase = (jc * 8 + j8) * 256 + wc * 64;
        float colpart[4] = {0.f, 0.f, 0.f, 0.f};
        #pragma unroll
        for (int m = 0; m < 4; ++m)
          #pragma unroll
          for (int n = 0; n < 4; ++n)
            #pragma unroll
            for (int g = 0; g < 4; ++g) {
              float ev = exp2f(acc[m][n][g]);
              rowAcc[m][g] += ev;
              colpart[n] += ev;
              acc[m][n][g] = 0.0f;
            }
        #pragma unroll
        for (int n = 0; n < 4; ++n) {
          float cs = colpart[n];
          cs += __shfl_xor(cs, 16);
          cs += __shfl_xor(cs, 32);
          if (q4 == n) {
            atomicAdd(&out[NB + colbase + n * 16 + lo16], cs);
          }
        }
      }
      __builtin_amdgcn_s_barrier();                  // slot-reuse protection
      asm volatile("" ::: "memory");
    }
  }

  // ---- final row reduction: rowAcc summed over lo16 group, one atomic/row ----
  #pragma unroll
  for (int m = 0; m < 4; ++m)
    #pragma unroll
    for (int g = 0; g < 4; ++g) {
      float rs = rowAcc[m][g];
      rs += __shfl_xor(rs, 1);
      rs += __shfl_xor(rs, 2);
      rs += __shfl_xor(rs, 4);
      rs += __shfl_xor(rs, 8);
      if (lo16 == m * 4 + g) {
        int row = bi * 128 + wr * 64 + m * 16 + q4 * 4 + g;
        atomicAdd(&out[row], rs);
      }
    }
}

extern "C" void kernel_launch(void* const* d_in, const int* in_sizes, int n_in,
                              void* d_out, int out_size, void* d_ws, size_t ws_size,
                              hipStream_t stream) {
  const float* e = (const float*)d_in[0];
  const float* v = (const float*)d_in[1];
  float* out = (float*)d_out;
  unsigned short* ebf = (unsigned short*)d_ws;
  unsigned short* vbf = ebf + (size_t)NB * DK;
  hipMemsetAsync(d_out, 0, (size_t)2 * NB * sizeof(float), stream);
  hipLaunchKernelGGL(norm_kernel, dim3((2 * NB) / 4), dim3(256), 0, stream, e, v, ebf, vbf);
  hipLaunchKernelGGL(score_kernel, dim3(256), dim3(512), 0, stream, ebf, vbf, out);
}

// Round 6
// 88.674 us; speedup vs baseline: 1.3029x; 1.0248x over previous
//
#include <hip/hip_runtime.h>
#include <hip/hip_bf16.h>
#include <stdint.h>

#define NB 8192
#define DK 256
// gamma * log2(e): epilogue uses native exp2
#define GSCALE 14.426950408889634f

typedef short short8 __attribute__((ext_vector_type(8)));
typedef float f32x4 __attribute__((ext_vector_type(4)));

__device__ __forceinline__ unsigned short f32_to_bf16(float f) {
  uint32_t u = __builtin_bit_cast(uint32_t, f);
  u += 0x7FFFu + ((u >> 16) & 1u);   // RNE
  return (unsigned short)(u >> 16);
}

// One wave per row: 1/max(||row||,eps); gamma*log2e folded into e side; store bf16.
__global__ __launch_bounds__(256) void norm_kernel(const float* __restrict__ e,
                                                   const float* __restrict__ v,
                                                   unsigned short* __restrict__ ebf,
                                                   unsigned short* __restrict__ vbf) {
  int wave = threadIdx.x >> 6;
  int lane = threadIdx.x & 63;
  int row = blockIdx.x * 4 + wave;
  const float* src;
  unsigned short* dst;
  float mul;
  if (row < NB) {
    src = e + (size_t)row * DK; dst = ebf + (size_t)row * DK; mul = GSCALE;
  } else {
    src = v + (size_t)(row - NB) * DK; dst = vbf + (size_t)(row - NB) * DK; mul = 1.0f;
  }
  float4 x = reinterpret_cast<const float4*>(src)[lane];
  float ss = x.x * x.x + x.y * x.y + x.z * x.z + x.w * x.w;
  #pragma unroll
  for (int off = 32; off >= 1; off >>= 1) ss += __shfl_xor(ss, off);
  float s = mul / fmaxf(sqrtf(ss), 1e-8f);
  ushort4 o;
  o.x = f32_to_bf16(x.x * s);
  o.y = f32_to_bf16(x.y * s);
  o.z = f32_to_bf16(x.z * s);
  o.w = f32_to_bf16(x.w * s);
  reinterpret_cast<ushort4*>(dst)[lane] = o;
}

// A-in-registers + LDS-broadcast B, counted-vmcnt pipeline (T3/T4).
// KEY CHANGE vs R5: zero global atomics inside the main loop. Col sums go to
// a per-block LDS array (ds_write, lgkm domain -> never pollutes the vmcnt
// queue); row sums stay in registers. All global atomics fire once at kernel
// end as a dependent-free burst. Main-loop vmcnt queue = stage loads only.
__global__ __launch_bounds__(512, 2) void score_kernel(const unsigned short* __restrict__ ebf,
                                                       const unsigned short* __restrict__ vbf,
                                                       float* __restrict__ out) {
  __shared__ unsigned short smem[2][16384];   // 2 x 32 KiB B double-buffer
  __shared__ float colsum[2][2048];           // per-wr col sums, 16 KiB

  const int tid = threadIdx.x;
  const int w = tid >> 6;          // 0..7
  const int lane = tid & 63;
  const int lo16 = lane & 15;
  const int q4 = lane >> 4;        // 0..3
  const int wr = w >> 2;           // 0..1 (M half, 64 rows)
  const int wc = w & 3;            // 0..3 (N quarter, 64 cols)

  // 256 blocks = 64 bi x 4 jc; XCD pair shares one jc chunk (L2 locality).
  int id = blockIdx.x;
  int xcd = id & 7;
  int s5 = id >> 3;
  int jc = xcd >> 1;                // 0..3
  int bi = s5 | ((xcd & 1) << 5);   // 0..63

  // ---- A panel direct to registers: row = bi*128+wr*64+m*16+lo16,
  //      A[m][s] holds k = s*32 + q4*8 .. +8 ----
  const char* eBase = (const char*)ebf;
  short8 A[4][8];
  #pragma unroll
  for (int m = 0; m < 4; ++m) {
    const char* rp = eBase + (size_t)(bi * 128 + wr * 64 + m * 16 + lo16) * 512 + q4 * 16;
    #pragma unroll
    for (int s = 0; s < 8; ++s)
      A[m][s] = *(const short8*)(rp + s * 64);
  }

  const char* vC = (const char*)vbf + (size_t)(jc * 2048) * 512;

  // Stage chunk c (j = c>>2, kt = c&3) into smem[c&1], swizzled (rule 21).
  auto stageB = [&](int c) {
    int buf = c & 1;
    const char* vP = vC + (size_t)(c >> 2) * 256 * 512;
    int ktoff = (c & 3) * 128;
    #pragma unroll
    for (int u = 0; u < 4; ++u) {
      int p = ((w * 4 + u) * 64 + lane) * 16;       // linear byte in 32 KiB chunk
      int r = p >> 7;                                // v-row (128 B rows)
      int lc = (p & 127) ^ ((r & 7) << 4);           // inverse-swizzled col
      size_t goff = (size_t)r * 512 + ktoff + lc;
      unsigned short* dst = &smem[buf][(w * 4 + u) * 512];
      __builtin_amdgcn_global_load_lds((const __attribute__((address_space(1))) uint32_t*)(vP + goff),
                                       (__attribute__((address_space(3))) uint32_t*)dst, 16, 0, 0);
    }
  };

  f32x4 acc[4][4];
  #pragma unroll
  for (int m = 0; m < 4; ++m)
    #pragma unroll
    for (int n = 0; n < 4; ++n)
      #pragma unroll
      for (int q = 0; q < 4; ++q)
        acc[m][n][q] = 0.0f;

  float rowAcc[4][4];
  #pragma unroll
  for (int m = 0; m < 4; ++m)
    #pragma unroll
    for (int g = 0; g < 4; ++g)
      rowAcc[m][g] = 0.0f;

  stageB(0);

  for (int j8 = 0; j8 < 8; ++j8) {
    #pragma unroll
    for (int kt = 0; kt < 4; ++kt) {
      const int c = j8 * 4 + kt;
      stageB((c + 1) & 31);                          // prefetch stays in flight
      asm volatile("s_waitcnt vmcnt(4)" ::: "memory");   // chunk c done, c+1 pending
      __builtin_amdgcn_s_barrier();                  // all waves' chunk-c writes visible
      asm volatile("" ::: "memory");
      const char* LB = (const char*)&smem[kt & 1][0];
      short8 bfr[2][4];
      #pragma unroll
      for (int ks = 0; ks < 2; ++ks)
        #pragma unroll
        for (int n = 0; n < 4; ++n) {
          int row = wc * 64 + n * 16 + lo16;
          int byte = row * 128 + ((ks * 64 + q4 * 16) ^ ((row & 7) << 4));
          bfr[ks][n] = *(const short8*)(LB + byte);
        }
      asm volatile("s_waitcnt lgkmcnt(0)" ::: "memory");
      __builtin_amdgcn_sched_barrier(0);             // rule #18: pin MFMA after wait
      __builtin_amdgcn_s_setprio(1);
      #pragma unroll
      for (int ks = 0; ks < 2; ++ks)
        #pragma unroll
        for (int m = 0; m < 4; ++m)
          #pragma unroll
          for (int n = 0; n < 4; ++n)
            acc[m][n] = __builtin_amdgcn_mfma_f32_16x16x32_bf16(A[m][kt * 2 + ks], bfr[ks][n], acc[m][n], 0, 0, 0);
      __builtin_amdgcn_s_setprio(0);

      if (kt == 3) {
        // ---- per-j epilogue: E = exp2(acc); rows -> regs, cols -> LDS.
        // NO global atomics here (they'd sit in the vmcnt queue and stall
        // the next phase's counted wait). Each local col is visited exactly
        // once per block, so a plain ds_write suffices.
        // C/D layout: col = lane&15 (B side), row = (lane>>4)*4 + reg (A side).
        int localbase = j8 * 256 + wc * 64;
        float colpart[4] = {0.f, 0.f, 0.f, 0.f};
        #pragma unroll
        for (int m = 0; m < 4; ++m)
          #pragma unroll
          for (int n = 0; n < 4; ++n)
            #pragma unroll
            for (int g = 0; g < 4; ++g) {
              float ev = exp2f(acc[m][n][g]);
              rowAcc[m][g] += ev;
              colpart[n] += ev;
              acc[m][n][g] = 0.0f;
            }
        #pragma unroll
        for (int n = 0; n < 4; ++n) {
          float cs = colpart[n];
          cs += __shfl_xor(cs, 16);
          cs += __shfl_xor(cs, 32);
          if (q4 == n) {
            colsum[wr][localbase + n * 16 + lo16] = cs;
          }
        }
      }
      __builtin_amdgcn_s_barrier();                  // slot-reuse protection
      asm volatile("" ::: "memory");
    }
  }

  // ---- tail: all global atomics in one dependent-free burst ----
  __syncthreads();   // drains stray wraparound prefetch + LDS writes

  // cols: merge wr copies, 2048 coalesced atomics per block
  #pragma unroll
  for (int k = 0; k < 4; ++k) {
    int c = tid + k * 512;
    float s = colsum[0][c] + colsum[1][c];
    atomicAdd(&out[NB + jc * 2048 + c], s);
  }

  // rows: shfl-reduce over lo16 group, one atomic per (row, wc-wave)
  #pragma unroll
  for (int m = 0; m < 4; ++m)
    #pragma unroll
    for (int g = 0; g < 4; ++g) {
      float rs = rowAcc[m][g];
      rs += __shfl_xor(rs, 1);
      rs += __shfl_xor(rs, 2);
      rs += __shfl_xor(rs, 4);
      rs += __shfl_xor(rs, 8);
      if (lo16 == m * 4 + g) {
        int row = bi * 128 + wr * 64 + m * 16 + q4 * 4 + g;
        atomicAdd(&out[row], rs);
      }
    }
}

extern "C" void kernel_launch(void* const* d_in, const int* in_sizes, int n_in,
                              void* d_out, int out_size, void* d_ws, size_t ws_size,
                              hipStream_t stream) {
  const float* e = (const float*)d_in[0];
  const float* v = (const float*)d_in[1];
  float* out = (float*)d_out;
  unsigned short* ebf = (unsigned short*)d_ws;
  unsigned short* vbf = ebf + (size_t)NB * DK;
  hipMemsetAsync(d_out, 0, (size_t)2 * NB * sizeof(float), stream);
  hipLaunchKernelGGL(norm_kernel, dim3((2 * NB) / 4), dim3(256), 0, stream, e, v, ebf, vbf);
  hipLaunchKernelGGL(score_kernel, dim3(256), dim3(512), 0, stream, ebf, vbf, out);
}